// Round 15
// baseline (654.715 us; speedup 1.0000x reference)
//
#include <hip/hip_runtime.h>
#include <math.h>

// HyenaFilter: y = irfft(rfft(x,2L) * rfft(k,2L))[..., :L] + x*bias
// Register-blocked mixed-radix [16,16,16,2] FFT. Round-15 revision:
//  - KF IN REGISTERS, GLOBAL Kf DELETED: thread tt computes filter bins
//    k=tt+1+it*512 / jj=4096-k in phase 1 and consumes exactly those bins in
//    every phase-2 spectral stage. Keep kvk[4]/kvj[4] (+ hoisted tw16 Wk[4],
//    + kv0 for tt==0) in registers; both spectral loops fully unrolled so all
//    kv indexing is compile-time (no scratch). Deletes 48 MB Kf writes and
//    ~200 MB of L2 kf reads + their issue/latency in the spectral intervals.
//  - keeps R14: filter merged into k_main (768 blocks = 3 exact rounds),
//    packed f32 cplx (v_pk_*), mask-14 swizzle + b128 LDS, pass-A twiddles in
//    registers (twA[15]), bias folded into the kf registers, sequential-paired
//    passes, two-row ping-pong, LDS twiddle tables, wave-local B<->C sync,
//    pruned first fwd pass, merged k_pre.

#define LSEQ 8192
#define NCH 768
#define NBATCH 8
#define NT 512            // threads per block

// ws layout (float offsets)
#define OFF_TWB  0        // 32 rows x 16 cplx : W16384^{32*q*m}   (pass B; pass-A high = rows 2b)
#define OFF_TW16 1024     // 2049 cplx         : W16384^k, k<=2048
#define OFF_TL   5124     // 32 rows x 16 cplx : W16384^{2*a*m}    (pass A low)
#define OFF_TWC  6660     // 2 rows x 16 cplx  : W16384^{512*p*m}  (pass C)
#define OFF_H    10240    // 8192 x 16 floats (MLP features, row-major)

typedef float cplx __attribute__((ext_vector_type(2)));

__device__ __forceinline__ cplx cmul(cplx a, cplx b){
    return cplx{a.x, a.x} * b + cplx{a.y, a.y} * cplx{-b.y, b.x};
}
__device__ __forceinline__ cplx mni(cplx a){ return cplx{a.y, -a.x}; }  // * -i

// wave-local LDS producer->consumer sync (exchange confined to one wave)
__device__ __forceinline__ void wave_sync(){
    asm volatile("s_waitcnt lgkmcnt(0)" ::: "memory");
}
// scheduling fence between the two sequential buffer-passes (R9 spill fix)
__device__ __forceinline__ void fence(){
    asm volatile("" ::: "memory");
}

// bit0-preserving swizzle (mask &14): pairs {2m,2m+1} stay adjacent, fixed order
__device__ __forceinline__ int IDX14(int i){ return i ^ (((i>>4) ^ (i>>8)) & 14); }
// digit-reversal: bin k -> slot after DIF passes [16(512),16(32),16(2)] (pre-r2, slot even)
__device__ __forceinline__ int drev(int k){
    return ((k & 15) << 9) | (((k >> 4) & 15) << 5) | (((k >> 8) & 15) << 1) | (k >> 12);
}

#define C1 0.923879532511286756f
#define S1 0.382683432365089772f
#define R2 0.707106781186547524f

// natural-in DFT-16; output bin m in q[rv[m]]. FULL=false: inputs 8..15 are
// pre-duplicated copies of 0..7 (zero upper half), stage-1 add/sub skipped.
template<bool FULL>
__device__ __forceinline__ void dft16(cplx q[16]) {
    if constexpr (FULL) {
#pragma unroll
        for (int j = 0; j < 8; ++j) { cplx u=q[j], v=q[j+8]; q[j]=u+v; q[j+8]=u-v; }
    }
    q[9]  = cmul(q[9],  cplx{ C1,-S1});
    q[10] = cmul(q[10], cplx{ R2,-R2});
    q[11] = cmul(q[11], cplx{ S1,-C1});
    q[12] = mni(q[12]);
    q[13] = cmul(q[13], cplx{-S1,-C1});
    q[14] = cmul(q[14], cplx{-R2,-R2});
    q[15] = cmul(q[15], cplx{-C1,-S1});
#pragma unroll
    for (int b = 0; b < 16; b += 8) {
#pragma unroll
        for (int j = 0; j < 4; ++j) { cplx u=q[b+j], v=q[b+j+4]; q[b+j]=u+v; q[b+j+4]=u-v; }
        q[b+5] = cmul(q[b+5], cplx{ R2,-R2});
        q[b+6] = mni(q[b+6]);
        q[b+7] = cmul(q[b+7], cplx{-R2,-R2});
    }
#pragma unroll
    for (int b = 0; b < 16; b += 4) {
        cplx u0=q[b], v0=q[b+2], u1=q[b+1], v1=q[b+3];
        q[b]=u0+v0; q[b+2]=u0-v0;
        q[b+1]=u1+v1; q[b+3]=mni(u1-v1);
    }
#pragma unroll
    for (int b = 0; b < 16; b += 2) { cplx u=q[b], v=q[b+1]; q[b]=u+v; q[b+1]=u-v; }
}

// Hand-folded swizzled addressing for mask &14: IDX14(base+p+r*L) == (sb ^ C_r) + (r*L).
template<int PASS>
__device__ __forceinline__ int psb(int t) {
    if constexpr (PASS == 0) {               // L=512, p=t
        return t ^ (((t>>4) ^ (t>>8)) & 14);
    } else if constexpr (PASS == 1) {        // L=32, base=(t>>5)<<9, p=t&31
        int p = t & 31, hb = t >> 5;
        return ((hb<<9) | p) ^ (((p>>4) ^ (hb<<1)) & 14);
    } else {                                 // L=2, base=(t>>1)<<5, p=t&1
        int h = t >> 1;
        return ((h<<5) | (t&1)) ^ (((h<<1) ^ (h>>3)) & 14);
    }
}
template<int PASS>
__device__ __forceinline__ int paddr(int sb, int r) {
    if constexpr (PASS == 0)      return (sb ^ (2*(r&7))) + (r<<9);
    else if constexpr (PASS == 1) return (sb ^ (2*(r&7))) + (r<<5);
    else                          return sb ^ (r<<1);
}

// One radix-16 pass (single buffer). Pass A twiddles come from registers
// (twA[15], hoisted — thread-constant); B/C from LDS table twT[m][row].
template<int PASS, bool DIT, bool PRUNED>
__device__ __forceinline__ void r16p(cplx* lds, const cplx (*twT)[68],
                                     const cplx (&twA)[15], int t) {
    static constexpr int RV[16] = {0,8,4,12,2,10,6,14,1,9,5,13,3,11,7,15};
    const int sb = psb<PASS>(t);
    int rL = 0;
    if constexpr (PASS == 1) { rL = t & 31; }
    else if constexpr (PASS == 2) { rL = 64 + (t & 1); }
    cplx q[16];
    if constexpr (PRUNED) {
#pragma unroll
        for (int r = 0; r < 8; ++r) { q[r] = lds[paddr<PASS>(sb, r)]; q[r+8] = q[r]; }
    } else {
#pragma unroll
        for (int r = 0; r < 16; ++r) q[r] = lds[paddr<PASS>(sb, r)];
    }
    if constexpr (DIT) {
#pragma unroll
        for (int m = 1; m < 16; ++m) {
            cplx w = (PASS == 0) ? twA[m-1] : twT[m][rL];
            q[m] = cmul(q[m], w);
        }
        dft16<true>(q);
    } else {
        dft16<!PRUNED>(q);
#pragma unroll
        for (int m = 1; m < 16; ++m) {
            cplx w = (PASS == 0) ? twA[m-1] : twT[m][rL];
            q[RV[m]] = cmul(q[RV[m]], w);
        }
    }
#pragma unroll
    for (int m = 0; m < 16; ++m) lds[paddr<PASS>(sb, m)] = q[RV[m]];
}

// paired pass: two sequential single-buffer passes, one barrier interval
template<int PASS, bool DIT, bool PRUNED>
__device__ __forceinline__ void r16pp(cplx* l0, cplx* l1, const cplx (*twT)[68],
                                      const cplx (&twA)[15], int t) {
    r16p<PASS, DIT, PRUNED>(l0, twT, twA, t);
    fence();
    r16p<PASS, DIT, PRUNED>(l1, twT, twA, t);
}

// copy twiddle tables global -> LDS (transposed): 66 rows x 16 elems
__device__ __forceinline__ void load_twT(cplx (*twT)[68], const float* __restrict__ ws, int tid) {
    const cplx* gTWB = (const cplx*)(ws + OFF_TWB);
    const cplx* gTL  = (const cplx*)(ws + OFF_TL);
    const cplx* gTWC = (const cplx*)(ws + OFF_TWC);
    for (int idx = tid; idx < 16*66; idx += NT) {
        int r = idx >> 4, m = idx & 15;
        cplx v;
        if (r < 32)      v = gTWB[(r << 4) + m];
        else if (r < 64) v = gTL[((r - 32) << 4) + m];
        else             v = gTWC[((r - 64) << 4) + m];
        twT[m][r] = v;
    }
}

// hoist pass-A combined twiddles into registers (thread-constant; call after
// twT is barrier-visible). W8192^{pm} = TL[t&31][m] * TWB[2*(t>>5)][m].
__device__ __forceinline__ void make_twA(cplx (&twA)[15], const cplx (*twT)[68], int t) {
    const int rL = 32 + (t & 31);
    const int rH = (t >> 5) << 1;
#pragma unroll
    for (int m = 1; m < 16; ++m) twA[m-1] = cmul(twT[m][rL], twT[m][rH]);
}

// spectral multiply for bin pair (k, 8192-k): o1/o2 are swapped v'[k], v'[8192-k]
__device__ __forceinline__ void specpair(cplx V1, cplx V2, float4 kv, cplx W,
                                         cplx& o1, cplx& o2) {
    cplx Eh = V1 + cplx{V2.x, -V2.y};
    cplx Oh = cplx{V1.y + V2.y, V2.x - V1.x};
    cplx S = cplx{kv.x, kv.y};
    float a = W.x*kv.z, b = W.y*kv.w, cc = W.x*kv.w, dd = W.y*kv.z;
    cplx T  = cplx{a - b, cc + dd};
    cplx T2 = cplx{a + b, cc - dd};
    cplx Ep = cmul(Eh, S) + cmul(Oh, T);
    cplx Op = cmul(Eh, T2) + cmul(Oh, S);
    o1 = cplx{Ep.y + Op.x, Ep.x - Op.y};
    o2 = cplx{Op.x - Ep.y, Ep.x + Op.y};
}

// fused fwd-r2 + spectral multiply + inverse-r2 for one buffer at slot pair
__device__ __forceinline__ void spec_rows(float4* l4, int sA, int sB,
                                          float4 kvk, float4 kvj, cplx W, cplx Wj) {
    float4 fA = l4[sA], fB = l4[sB];
    cplx uA = {fA.x, fA.y}, vA = {fA.z, fA.w};
    cplx uB = {fB.x, fB.y}, vB = {fB.z, fB.w};
    cplx Vk = uA + vA, Vk4 = uA - vA;   // bins k, k+4096
    cplx Vj = uB + vB, Vj4 = uB - vB;   // bins jj, 8192-k
    cplx r1, r2, r1j, r2j;
    specpair(Vk, Vj4, kvk, W,  r1,  r2);   // v'[k],  v'[8192-k]
    specpair(Vj, Vk4, kvj, Wj, r1j, r2j);  // v'[jj], v'[4096+k]
    cplx a0 = r1 + r2j, a1 = r1 - r2j;
    cplx b0 = r1j + r2, b1 = r1j - r2;
    l4[sA] = make_float4(a0.x, a0.y, a1.x, a1.y);
    l4[sB] = make_float4(b0.x, b0.y, b1.x, b1.y);
}

// bins 0 / 4096 special (tt==0); slots {0,1} = l4[0]
__device__ __forceinline__ void spec_dc(float4* l4, float4 kv) {
    float4 f = l4[0];
    cplx u = {f.x, f.y}, v = {f.z, f.w};
    cplx V0 = u + v, VN = u - v;
    float U0 = V0.x + V0.y, UL = V0.x - V0.y;
    float re = U0*kv.x + UL*kv.y;
    float im = U0*kv.x - UL*kv.y;
    cplx s0 = {im, re};
    cplx P = {VN.x*kv.z + VN.y*kv.w, VN.x*kv.w - VN.y*kv.z};
    cplx s1 = {-P.y, P.x};
    cplx a = s0 + s1, b = s0 - s1;
    l4[0] = make_float4(a.x, a.y, b.x, b.y);
}

// filter spectral for one channel at quad (k,jj), bias folded (E += eb):
// RESULTS GO TO REGISTERS (okk, okj) — no global store.
__device__ __forceinline__ void filt_reg(const float4* l4, int sA, int sB,
                                         cplx W, cplx Wj, float sc, float eb,
                                         float4& okk, float4& okj) {
    float4 fA = l4[sA], fB = l4[sB];
    cplx uA = {fA.x, fA.y}, vA = {fA.z, fA.w};
    cplx uB = {fB.x, fB.y}, vB = {fB.z, fB.w};
    cplx Vk = uA + vA, Vk4 = uA - vA;
    cplx Vj = uB + vB, Vj4 = uB - vB;
    {
        cplx E = {Vk.x + Vj4.x + eb, Vk.y - Vj4.y};
        cplx O = {Vk.y + Vj4.y, Vj4.x - Vk.x};
        cplx D = cmul(W, O);
        okk = make_float4(E.x*sc, E.y*sc, D.x*sc, D.y*sc);
    }
    {
        cplx E = {Vj.x + Vk4.x + eb, Vj.y - Vk4.y};
        cplx O = {Vj.y + Vk4.y, Vk4.x - Vj.x};
        cplx D = cmul(Wj, O);
        okj = make_float4(E.x*sc, E.y*sc, D.x*sc, D.y*sc);
    }
}
// DC with bias fold: H[0]+=bc, H[8192]+=bc, H[4096]+=bc. Returns register value.
__device__ __forceinline__ float4 filt_dc_reg(const float4* l4, float bc) {
    float4 f = l4[0];
    cplx u = {f.x, f.y}, v = {f.z, f.w};
    cplx V0 = u + v, VN = u - v;
    return make_float4((V0.x + V0.y + bc)/16384.f, (V0.x - V0.y + bc)/16384.f,
                       (VN.x + bc)/8192.f, -VN.y/8192.f);
}

// merged init (block 0: twiddle tables via double-precision factor tables) + MLP (blocks 1..16)
__global__ __launch_bounds__(512) void k_pre(const float* __restrict__ z, const float* __restrict__ freq,
        const float* __restrict__ W0, const float* __restrict__ b0,
        const float* __restrict__ W1, const float* __restrict__ b1,
        const float* __restrict__ W2, const float* __restrict__ b2,
        float* __restrict__ ws, float* __restrict__ H) {
    __shared__ double2 lA[128], lB[128];
    const int t = threadIdx.x;
    if (blockIdx.x == 0) {
        const double K = -2.0 * 3.14159265358979323846 / 16384.0;
        if (t < 128)      { double a = K * (double)(t << 7); lA[t] = make_double2(cos(a), sin(a)); }
        else if (t < 256) { int b = t - 128; double a = K * (double)b; lB[b] = make_double2(cos(a), sin(a)); }
        __syncthreads();
        auto wf = [&](int e) -> float2 {
            e &= 16383;
            double2 A = lA[e >> 7], B = lB[e & 127];
            return make_float2((float)(A.x*B.x - A.y*B.y), (float)(A.x*B.y + A.y*B.x));
        };
        float2* tw16 = (float2*)(ws + OFF_TW16);
        for (int k = t; k <= 2048; k += 512) tw16[k] = wf(k);
        if (t < 32) {
            float2* rowL = (float2*)(ws + OFF_TL)  + (t << 4);
            float2* rowB = (float2*)(ws + OFF_TWB) + (t << 4);
#pragma unroll
            for (int m = 0; m < 16; ++m) { rowL[m] = wf(2*t*m); rowB[m] = wf(32*t*m); }
        } else if (t < 34) {
            int c2 = t - 32;
            float2* rowC = (float2*)(ws + OFF_TWC) + (c2 << 4);
#pragma unroll
            for (int m = 0; m < 16; ++m) rowC[m] = wf(512*c2*m);
        }
    } else {
        const int j = ((blockIdx.x - 1) << 9) + t;
        const float z0 = z[j*3+0], z1 = z[j*3+1], z2 = z[j*3+2];
        float h[16], g[16];
#pragma unroll
        for (int m = 0; m < 16; ++m)
            h[m] = sinf(freq[m] * (z0*W0[m] + z1*W0[16+m] + z2*W0[32+m] + b0[m]));
#pragma unroll
        for (int m = 0; m < 16; ++m) {
            float a = b1[m];
#pragma unroll
            for (int p = 0; p < 16; ++p) a += h[p] * W1[p*16+m];
            g[m] = sinf(freq[m] * a);
        }
#pragma unroll
        for (int m = 0; m < 16; ++m) {
            float a = b2[m];
#pragma unroll
            for (int p = 0; p < 16; ++p) a += g[p] * W2[p*16+m];
            h[m] = sinf(freq[m] * a);
        }
        float4* hp = (float4*)(H + (j << 4));   // row-major [8192][16]
        hp[0] = make_float4(h[0],  h[1],  h[2],  h[3]);
        hp[1] = make_float4(h[4],  h[5],  h[6],  h[7]);
        hp[2] = make_float4(h[8],  h[9],  h[10], h[11]);
        hp[3] = make_float4(h[12], h[13], h[14], h[15]);
    }
}

// Block = channel c (768 blocks = 3 exact rounds). Phase 1: compute filter
// spectrum for THIS THREAD'S bins into registers (MLP staging -> pruned fwd
// FFT in l0 -> filt_reg). Phase 2: 8 batches as 4 ping-pong row-pairs using
// the register kf values (no global Kf at all). Bias folded into kf.
__global__ __launch_bounds__(NT) void k_main(const float* __restrict__ x, const float* __restrict__ H,
        const float* __restrict__ t, const float* __restrict__ deltas,
        const float* __restrict__ W3, const float* __restrict__ b3,
        const float* __restrict__ bias, const float* __restrict__ ws,
        float* __restrict__ out) {
    __shared__ alignas(16) cplx lds2[2][LSEQ];
    __shared__ cplx twT[16][68];
    const int c = blockIdx.x;                   // 0..767
    const int tt = threadIdx.x;
    cplx* l0 = lds2[0];
    cplx* l1 = lds2[1];
    float4* l04 = (float4*)l0;
    float4* l14 = (float4*)l1;
    const cplx* tw16 = (const cplx*)(ws + OFF_TW16);
    const size_t rowstride = (size_t)NCH * LSEQ;
    const float* xcol = x + (size_t)c * LSEQ;
    float* ocol = out + (size_t)c * LSEQ;
    const float sc = 1.0f / 32768.0f;

    // staging slot: IDX14(2i),IDX14(2i+1) = one float4 at ((EB^(j<<2))+(j<<10))>>1
    const int EB = (tt << 1) ^ (((tt>>3) ^ (tt>>7)) & 14);
    const int sbA = psb<0>(tt);

    load_twT(twT, ws, tt);

    // ---- Phase 1: filter for channel c -> l0 -> fwd FFT -> registers ----
    {
        float4 w3a = make_float4(W3[0*NCH+c],  W3[1*NCH+c],  W3[2*NCH+c],  W3[3*NCH+c]);
        float4 w3b = make_float4(W3[4*NCH+c],  W3[5*NCH+c],  W3[6*NCH+c],  W3[7*NCH+c]);
        float4 w3c = make_float4(W3[8*NCH+c],  W3[9*NCH+c],  W3[10*NCH+c], W3[11*NCH+c]);
        float4 w3d = make_float4(W3[12*NCH+c], W3[13*NCH+c], W3[14*NCH+c], W3[15*NCH+c]);
        const float b3c = b3[c];
        const float ad = fabsf(deltas[c]);
#pragma unroll 1
        for (int j = 0; j < 8; ++j) {
            int n = tt + (j << 9);
            const float4* hp = (const float4*)(H + (n << 5));
            float4 p0 = hp[0], p1 = hp[1], p2 = hp[2], p3 = hp[3];
            float4 q0 = hp[4], q1 = hp[5], q2 = hp[6], q3 = hp[7];
            float s0 = b3c + p0.x*w3a.x + p0.y*w3a.y + p0.z*w3a.z + p0.w*w3a.w
                           + p1.x*w3b.x + p1.y*w3b.y + p1.z*w3b.z + p1.w*w3b.w
                           + p2.x*w3c.x + p2.y*w3c.y + p2.z*w3c.z + p2.w*w3c.w
                           + p3.x*w3d.x + p3.y*w3d.y + p3.z*w3d.z + p3.w*w3d.w;
            float s1 = b3c + q0.x*w3a.x + q0.y*w3a.y + q0.z*w3a.z + q0.w*w3a.w
                           + q1.x*w3b.x + q1.y*w3b.y + q1.z*w3b.z + q1.w*w3b.w
                           + q2.x*w3c.x + q2.y*w3c.y + q2.z*w3c.z + q2.w*w3c.w
                           + q3.x*w3d.x + q3.y*w3d.y + q3.z*w3d.z + q3.w*w3d.w;
            float2 tv = ((const float2*)t)[n];
            l0[paddr<0>(sbA, j)] = cplx{s0 * expf(-tv.x*ad), s1 * expf(-tv.y*ad)};
        }
    }
    __syncthreads();                            // covers twT copy + filter staging
    cplx twA[15];
    make_twA(twA, twT, tt);

    r16p<0,false,true >(l0, twT, twA, tt); __syncthreads();
    r16p<1,false,false>(l0, twT, twA, tt); wave_sync();
    r16p<2,false,false>(l0, twT, twA, tt); __syncthreads();

    // filter spectrum for this thread's bins -> registers (fully unrolled:
    // static indexing keeps kv/W in VGPRs, not scratch)
    float4 kvk[4], kvj[4];
    cplx Wk[4];
    float4 kv0 = make_float4(0.f, 0.f, 0.f, 0.f);
    {
        const float bc = bias[c];
        const float eb = 2.0f * bc;
#pragma unroll
        for (int it = 0; it < 4; ++it) {
            int k  = tt + 1 + (it << 9);   // 1..2048
            int jj = 4096 - k;             // (k=2048: kvk==kvj, identical math)
            int sA = IDX14(drev(k)) >> 1, sB = IDX14(drev(jj)) >> 1;
            cplx W  = tw16[k];
            Wk[it] = W;
            cplx Wj = cplx{-W.y, -W.x};
            filt_reg(l04, sA, sB, W, Wj, sc, eb, kvk[it], kvj[it]);
        }
        if (tt == 0) kv0 = filt_dc_reg(l04, bc);
    }
    __syncthreads();   // protect l0 before phase-2 staging

    // ---- Phase 2: 8 batches as 4 ping-pong pairs (kf from registers) ----
#pragma unroll 1
    for (int pp = 0; pp < 4; ++pp) {            // pair = batches (2pp, 2pp+1)
        const float4* xr0 = (const float4*)(xcol + (size_t)(2*pp)     * rowstride);
        const float4* xr1 = (const float4*)(xcol + (size_t)(2*pp + 1) * rowstride);
#pragma unroll
        for (int j = 0; j < 4; ++j) {
            int si = ((EB ^ (j<<2)) + (j<<10)) >> 1;
            l04[si] = xr0[tt + (j<<9)];
            l14[si] = xr1[tt + (j<<9)];
        }
        __syncthreads();
        r16pp<0,false,true >(l0, l1, twT, twA, tt); __syncthreads();
        r16pp<1,false,false>(l0, l1, twT, twA, tt); wave_sync();
        r16pp<2,false,false>(l0, l1, twT, twA, tt); __syncthreads();

        // fused fwd-r2 + spectral + inverse-r2 on both buffers; kf/W registers
#pragma unroll
        for (int it = 0; it < 4; ++it) {
            int k  = tt + 1 + (it << 9);   // 1..2048
            int jj = 4096 - k;
            int sA = IDX14(drev(k)) >> 1, sB = IDX14(drev(jj)) >> 1;
            cplx W  = Wk[it];
            cplx Wj = cplx{-W.y, -W.x};
            spec_rows(l04, sA, sB, kvk[it], kvj[it], W, Wj);
            spec_rows(l14, sA, sB, kvk[it], kvj[it], W, Wj);
        }
        if (tt == 0) {
            spec_dc(l04, kv0);
            spec_dc(l14, kv0);
        }
        __syncthreads();

        r16pp<2,true,false>(l0, l1, twT, twA, tt); wave_sync();
        r16pp<1,true,false>(l0, l1, twT, twA, tt); __syncthreads();
        r16pp<0,true,false>(l0, l1, twT, twA, tt); __syncthreads();

        float4* o0 = (float4*)(ocol + (size_t)(2*pp)     * rowstride);
        float4* o1 = (float4*)(ocol + (size_t)(2*pp + 1) * rowstride);
#pragma unroll
        for (int j = 0; j < 4; ++j) {
            int si = ((EB ^ (j<<2)) + (j<<10)) >> 1;
            float4 f0 = l04[si], f1 = l14[si];
            o0[tt + (j<<9)] = make_float4(f0.y, f0.x, f0.w, f0.z);
            o1[tt + (j<<9)] = make_float4(f1.y, f1.x, f1.w, f1.z);
        }
        if (pp < 3) __syncthreads();   // protect lds before next pair's staging
    }
}

extern "C" void kernel_launch(void* const* d_in, const int* in_sizes, int n_in,
                              void* d_out, int out_size, void* d_ws, size_t ws_size,
                              hipStream_t stream) {
    const float* x      = (const float*)d_in[0];
    const float* z      = (const float*)d_in[2];
    const float* t      = (const float*)d_in[3];
    const float* deltas = (const float*)d_in[4];
    const float* freq   = (const float*)d_in[5];
    const float* W0     = (const float*)d_in[6];
    const float* b0     = (const float*)d_in[7];
    const float* W1     = (const float*)d_in[8];
    const float* b1     = (const float*)d_in[9];
    const float* W2     = (const float*)d_in[10];
    const float* b2     = (const float*)d_in[11];
    const float* W3     = (const float*)d_in[12];
    const float* b3     = (const float*)d_in[13];
    const float* bias   = (const float*)d_in[14];
    float* out = (float*)d_out;
    float* ws  = (float*)d_ws;
    float* H   = ws + OFF_H;

    hipLaunchKernelGGL(k_pre, dim3(17), dim3(512), 0, stream, z, freq, W0, b0, W1, b1, W2, b2, ws, H);
    hipLaunchKernelGGL(k_main, dim3(NCH), dim3(NT), 0, stream, x, H, t, deltas, W3, b3, bias, ws, out);
}

// Round 16
// 607.047 us; speedup vs baseline: 1.0785x; 1.0785x over previous
//
#include <hip/hip_runtime.h>
#include <math.h>

// HyenaFilter: y = irfft(rfft(x,2L) * rfft(k,2L))[..., :L] + x*bias
// Register-blocked mixed-radix [16,16,16,2] FFT. Round-16 revision:
//  - REVERT R15 (register-Kf spilled: VGPR=128, ~100MB scratch, k_main 405).
//    Back to R14's global-Kf merged kernel.
//  - TWA HOIST REMOVED: the R12->R13 A/B showed the pass-A register hoist made
//    k_main slower (302->308, +30 persistent VGPR shrank per-pass ILP) while
//    its benefit targeted the now-merged filter. Phase 2 has 16 A-calls (hurt
//    scales) vs 1 in phase 1 (help doesn't). Pass-A twiddles again combined
//    from LDS: W8192^{pm} = TL[p&31][m] * TWB[2(p>>5)][m]. VGPR ~88-92.
//  - keeps R14: filter merged into k_main (768 blocks = 3 exact rounds, global
//    Kf written once per channel then read L2-hot), packed f32 cplx (v_pk_*),
//    mask-14 swizzle + b128 LDS, bias folded into Kf, sequential-paired
//    passes, two-row ping-pong, LDS twiddle tables, wave-local B<->C sync,
//    pruned first fwd pass, merged k_pre.

#define LSEQ 8192
#define NCH 768
#define NBATCH 8
#define NT 512            // threads per block

// ws layout (float offsets)
#define OFF_TWB  0        // 32 rows x 16 cplx : W16384^{32*q*m}   (pass B; pass-A high = rows 2b)
#define OFF_TW16 1024     // 2049 cplx         : W16384^k, k<=2048
#define OFF_TL   5124     // 32 rows x 16 cplx : W16384^{2*a*m}    (pass A low)
#define OFF_TWC  6660     // 2 rows x 16 cplx  : W16384^{512*p*m}  (pass C)
#define OFF_H    10240    // 8192 x 16 floats (MLP features, row-major)
#define OFF_KF   141312   // 768 x 4096 float4 (S~, D~ per bin pair)

typedef float cplx __attribute__((ext_vector_type(2)));

__device__ __forceinline__ cplx cmul(cplx a, cplx b){
    return cplx{a.x, a.x} * b + cplx{a.y, a.y} * cplx{-b.y, b.x};
}
__device__ __forceinline__ cplx mni(cplx a){ return cplx{a.y, -a.x}; }  // * -i

// wave-local LDS producer->consumer sync (exchange confined to one wave)
__device__ __forceinline__ void wave_sync(){
    asm volatile("s_waitcnt lgkmcnt(0)" ::: "memory");
}
// scheduling fence between the two sequential buffer-passes (R9 spill fix)
__device__ __forceinline__ void fence(){
    asm volatile("" ::: "memory");
}

// bit0-preserving swizzle (mask &14): pairs {2m,2m+1} stay adjacent, fixed order
__device__ __forceinline__ int IDX14(int i){ return i ^ (((i>>4) ^ (i>>8)) & 14); }
// digit-reversal: bin k -> slot after DIF passes [16(512),16(32),16(2)] (pre-r2, slot even)
__device__ __forceinline__ int drev(int k){
    return ((k & 15) << 9) | (((k >> 4) & 15) << 5) | (((k >> 8) & 15) << 1) | (k >> 12);
}

#define C1 0.923879532511286756f
#define S1 0.382683432365089772f
#define R2 0.707106781186547524f

// natural-in DFT-16; output bin m in q[rv[m]]. FULL=false: inputs 8..15 are
// pre-duplicated copies of 0..7 (zero upper half), stage-1 add/sub skipped.
template<bool FULL>
__device__ __forceinline__ void dft16(cplx q[16]) {
    if constexpr (FULL) {
#pragma unroll
        for (int j = 0; j < 8; ++j) { cplx u=q[j], v=q[j+8]; q[j]=u+v; q[j+8]=u-v; }
    }
    q[9]  = cmul(q[9],  cplx{ C1,-S1});
    q[10] = cmul(q[10], cplx{ R2,-R2});
    q[11] = cmul(q[11], cplx{ S1,-C1});
    q[12] = mni(q[12]);
    q[13] = cmul(q[13], cplx{-S1,-C1});
    q[14] = cmul(q[14], cplx{-R2,-R2});
    q[15] = cmul(q[15], cplx{-C1,-S1});
#pragma unroll
    for (int b = 0; b < 16; b += 8) {
#pragma unroll
        for (int j = 0; j < 4; ++j) { cplx u=q[b+j], v=q[b+j+4]; q[b+j]=u+v; q[b+j+4]=u-v; }
        q[b+5] = cmul(q[b+5], cplx{ R2,-R2});
        q[b+6] = mni(q[b+6]);
        q[b+7] = cmul(q[b+7], cplx{-R2,-R2});
    }
#pragma unroll
    for (int b = 0; b < 16; b += 4) {
        cplx u0=q[b], v0=q[b+2], u1=q[b+1], v1=q[b+3];
        q[b]=u0+v0; q[b+2]=u0-v0;
        q[b+1]=u1+v1; q[b+3]=mni(u1-v1);
    }
#pragma unroll
    for (int b = 0; b < 16; b += 2) { cplx u=q[b], v=q[b+1]; q[b]=u+v; q[b+1]=u-v; }
}

// Hand-folded swizzled addressing for mask &14: IDX14(base+p+r*L) == (sb ^ C_r) + (r*L).
template<int PASS>
__device__ __forceinline__ int psb(int t) {
    if constexpr (PASS == 0) {               // L=512, p=t
        return t ^ (((t>>4) ^ (t>>8)) & 14);
    } else if constexpr (PASS == 1) {        // L=32, base=(t>>5)<<9, p=t&31
        int p = t & 31, hb = t >> 5;
        return ((hb<<9) | p) ^ (((p>>4) ^ (hb<<1)) & 14);
    } else {                                 // L=2, base=(t>>1)<<5, p=t&1
        int h = t >> 1;
        return ((h<<5) | (t&1)) ^ (((h<<1) ^ (h>>3)) & 14);
    }
}
template<int PASS>
__device__ __forceinline__ int paddr(int sb, int r) {
    if constexpr (PASS == 0)      return (sb ^ (2*(r&7))) + (r<<9);
    else if constexpr (PASS == 1) return (sb ^ (2*(r&7))) + (r<<5);
    else                          return sb ^ (r<<1);
}

// One radix-16 pass (single buffer), twiddles from LDS table twT[m][row]:
//   row<32: TWB[q][m]=W16384^{32qm}; row=32+a: TL[a][m]=W16384^{2am}; row=64+c: TWC[c][m].
// Pass A twiddle W8192^{pm} = TL[p&31][m] * TWB[2*(p>>5)][m] (combined inline;
// register hoist removed — R12/R13 A/B showed it cost ILP in the hot passes).
template<int PASS, bool DIT, bool PRUNED>
__device__ __forceinline__ void r16p(cplx* lds, const cplx (*twT)[68], int t) {
    static constexpr int RV[16] = {0,8,4,12,2,10,6,14,1,9,5,13,3,11,7,15};
    const int sb = psb<PASS>(t);
    int rL, rH = 0;
    if constexpr (PASS == 0) { rL = 32 + (t & 31); rH = (t >> 5) << 1; }
    else if constexpr (PASS == 1) { rL = t & 31; }
    else { rL = 64 + (t & 1); }
    cplx q[16];
    if constexpr (PRUNED) {
#pragma unroll
        for (int r = 0; r < 8; ++r) { q[r] = lds[paddr<PASS>(sb, r)]; q[r+8] = q[r]; }
    } else {
#pragma unroll
        for (int r = 0; r < 16; ++r) q[r] = lds[paddr<PASS>(sb, r)];
    }
    if constexpr (DIT) {
#pragma unroll
        for (int m = 1; m < 16; ++m) {
            cplx w = twT[m][rL];
            if constexpr (PASS == 0) w = cmul(w, twT[m][rH]);
            q[m] = cmul(q[m], w);
        }
        dft16<true>(q);
    } else {
        dft16<!PRUNED>(q);
#pragma unroll
        for (int m = 1; m < 16; ++m) {
            cplx w = twT[m][rL];
            if constexpr (PASS == 0) w = cmul(w, twT[m][rH]);
            q[RV[m]] = cmul(q[RV[m]], w);
        }
    }
#pragma unroll
    for (int m = 0; m < 16; ++m) lds[paddr<PASS>(sb, m)] = q[RV[m]];
}

// paired pass: two sequential single-buffer passes, one barrier interval
template<int PASS, bool DIT, bool PRUNED>
__device__ __forceinline__ void r16pp(cplx* l0, cplx* l1, const cplx (*twT)[68], int t) {
    r16p<PASS, DIT, PRUNED>(l0, twT, t);
    fence();
    r16p<PASS, DIT, PRUNED>(l1, twT, t);
}

// copy twiddle tables global -> LDS (transposed): 66 rows x 16 elems
__device__ __forceinline__ void load_twT(cplx (*twT)[68], const float* __restrict__ ws, int tid) {
    const cplx* gTWB = (const cplx*)(ws + OFF_TWB);
    const cplx* gTL  = (const cplx*)(ws + OFF_TL);
    const cplx* gTWC = (const cplx*)(ws + OFF_TWC);
    for (int idx = tid; idx < 16*66; idx += NT) {
        int r = idx >> 4, m = idx & 15;
        cplx v;
        if (r < 32)      v = gTWB[(r << 4) + m];
        else if (r < 64) v = gTL[((r - 32) << 4) + m];
        else             v = gTWC[((r - 64) << 4) + m];
        twT[m][r] = v;
    }
}

// spectral multiply for bin pair (k, 8192-k): o1/o2 are swapped v'[k], v'[8192-k]
__device__ __forceinline__ void specpair(cplx V1, cplx V2, float4 kv, cplx W,
                                         cplx& o1, cplx& o2) {
    cplx Eh = V1 + cplx{V2.x, -V2.y};
    cplx Oh = cplx{V1.y + V2.y, V2.x - V1.x};
    cplx S = cplx{kv.x, kv.y};
    float a = W.x*kv.z, b = W.y*kv.w, cc = W.x*kv.w, dd = W.y*kv.z;
    cplx T  = cplx{a - b, cc + dd};
    cplx T2 = cplx{a + b, cc - dd};
    cplx Ep = cmul(Eh, S) + cmul(Oh, T);
    cplx Op = cmul(Eh, T2) + cmul(Oh, S);
    o1 = cplx{Ep.y + Op.x, Ep.x - Op.y};
    o2 = cplx{Op.x - Ep.y, Ep.x + Op.y};
}

// fused fwd-r2 + spectral multiply + inverse-r2 for one buffer at slot pair
__device__ __forceinline__ void spec_rows(float4* l4, int sA, int sB,
                                          float4 kvk, float4 kvj, cplx W, cplx Wj) {
    float4 fA = l4[sA], fB = l4[sB];
    cplx uA = {fA.x, fA.y}, vA = {fA.z, fA.w};
    cplx uB = {fB.x, fB.y}, vB = {fB.z, fB.w};
    cplx Vk = uA + vA, Vk4 = uA - vA;   // bins k, k+4096
    cplx Vj = uB + vB, Vj4 = uB - vB;   // bins jj, 8192-k
    cplx r1, r2, r1j, r2j;
    specpair(Vk, Vj4, kvk, W,  r1,  r2);   // v'[k],  v'[8192-k]
    specpair(Vj, Vk4, kvj, Wj, r1j, r2j);  // v'[jj], v'[4096+k]
    cplx a0 = r1 + r2j, a1 = r1 - r2j;
    cplx b0 = r1j + r2, b1 = r1j - r2;
    l4[sA] = make_float4(a0.x, a0.y, a1.x, a1.y);
    l4[sB] = make_float4(b0.x, b0.y, b1.x, b1.y);
}

// bins 0 / 4096 special (tt==0); slots {0,1} = l4[0]
__device__ __forceinline__ void spec_dc(float4* l4, float4 kv) {
    float4 f = l4[0];
    cplx u = {f.x, f.y}, v = {f.z, f.w};
    cplx V0 = u + v, VN = u - v;
    float U0 = V0.x + V0.y, UL = V0.x - V0.y;
    float re = U0*kv.x + UL*kv.y;
    float im = U0*kv.x - UL*kv.y;
    cplx s0 = {im, re};
    cplx P = {VN.x*kv.z + VN.y*kv.w, VN.x*kv.w - VN.y*kv.z};
    cplx s1 = {-P.y, P.x};
    cplx a = s0 + s1, b = s0 - s1;
    l4[0] = make_float4(a.x, a.y, b.x, b.y);
}

// filter spectral store for one channel at quad (k,jj), bias folded (E += eb)
__device__ __forceinline__ void filt_store(const float4* l4, float4* kf, int k, int jj,
                                           int sA, int sB, cplx W, cplx Wj,
                                           float sc, float eb) {
    float4 fA = l4[sA], fB = l4[sB];
    cplx uA = {fA.x, fA.y}, vA = {fA.z, fA.w};
    cplx uB = {fB.x, fB.y}, vB = {fB.z, fB.w};
    cplx Vk = uA + vA, Vk4 = uA - vA;
    cplx Vj = uB + vB, Vj4 = uB - vB;
    {
        cplx E = {Vk.x + Vj4.x + eb, Vk.y - Vj4.y};
        cplx O = {Vk.y + Vj4.y, Vj4.x - Vk.x};
        cplx D = cmul(W, O);
        kf[k] = make_float4(E.x*sc, E.y*sc, D.x*sc, D.y*sc);
    }
    {
        cplx E = {Vj.x + Vk4.x + eb, Vj.y - Vk4.y};
        cplx O = {Vj.y + Vk4.y, Vk4.x - Vj.x};
        cplx D = cmul(Wj, O);
        kf[jj] = make_float4(E.x*sc, E.y*sc, D.x*sc, D.y*sc);
    }
}
// DC store with bias fold: H[0]+=bc, H[8192]+=bc, H[4096]+=bc.
__device__ __forceinline__ void filt_dc(const float4* l4, float4* kf, float bc) {
    float4 f = l4[0];
    cplx u = {f.x, f.y}, v = {f.z, f.w};
    cplx V0 = u + v, VN = u - v;
    kf[0] = make_float4((V0.x + V0.y + bc)/16384.f, (V0.x - V0.y + bc)/16384.f,
                        (VN.x + bc)/8192.f, -VN.y/8192.f);
}

// merged init (block 0: twiddle tables via double-precision factor tables) + MLP (blocks 1..16)
__global__ __launch_bounds__(512) void k_pre(const float* __restrict__ z, const float* __restrict__ freq,
        const float* __restrict__ W0, const float* __restrict__ b0,
        const float* __restrict__ W1, const float* __restrict__ b1,
        const float* __restrict__ W2, const float* __restrict__ b2,
        float* __restrict__ ws, float* __restrict__ H) {
    __shared__ double2 lA[128], lB[128];
    const int t = threadIdx.x;
    if (blockIdx.x == 0) {
        const double K = -2.0 * 3.14159265358979323846 / 16384.0;
        if (t < 128)      { double a = K * (double)(t << 7); lA[t] = make_double2(cos(a), sin(a)); }
        else if (t < 256) { int b = t - 128; double a = K * (double)b; lB[b] = make_double2(cos(a), sin(a)); }
        __syncthreads();
        auto wf = [&](int e) -> float2 {
            e &= 16383;
            double2 A = lA[e >> 7], B = lB[e & 127];
            return make_float2((float)(A.x*B.x - A.y*B.y), (float)(A.x*B.y + A.y*B.x));
        };
        float2* tw16 = (float2*)(ws + OFF_TW16);
        for (int k = t; k <= 2048; k += 512) tw16[k] = wf(k);
        if (t < 32) {
            float2* rowL = (float2*)(ws + OFF_TL)  + (t << 4);
            float2* rowB = (float2*)(ws + OFF_TWB) + (t << 4);
#pragma unroll
            for (int m = 0; m < 16; ++m) { rowL[m] = wf(2*t*m); rowB[m] = wf(32*t*m); }
        } else if (t < 34) {
            int c2 = t - 32;
            float2* rowC = (float2*)(ws + OFF_TWC) + (c2 << 4);
#pragma unroll
            for (int m = 0; m < 16; ++m) rowC[m] = wf(512*c2*m);
        }
    } else {
        const int j = ((blockIdx.x - 1) << 9) + t;
        const float z0 = z[j*3+0], z1 = z[j*3+1], z2 = z[j*3+2];
        float h[16], g[16];
#pragma unroll
        for (int m = 0; m < 16; ++m)
            h[m] = sinf(freq[m] * (z0*W0[m] + z1*W0[16+m] + z2*W0[32+m] + b0[m]));
#pragma unroll
        for (int m = 0; m < 16; ++m) {
            float a = b1[m];
#pragma unroll
            for (int p = 0; p < 16; ++p) a += h[p] * W1[p*16+m];
            g[m] = sinf(freq[m] * a);
        }
#pragma unroll
        for (int m = 0; m < 16; ++m) {
            float a = b2[m];
#pragma unroll
            for (int p = 0; p < 16; ++p) a += g[p] * W2[p*16+m];
            h[m] = sinf(freq[m] * a);
        }
        float4* hp = (float4*)(H + (j << 4));   // row-major [8192][16]
        hp[0] = make_float4(h[0],  h[1],  h[2],  h[3]);
        hp[1] = make_float4(h[4],  h[5],  h[6],  h[7]);
        hp[2] = make_float4(h[8],  h[9],  h[10], h[11]);
        hp[3] = make_float4(h[12], h[13], h[14], h[15]);
    }
}

// Block = channel c (768 blocks = 3 exact rounds). Phase 1: compute filter
// spectrum Kf[c] (MLP staging -> pruned fwd FFT in l0 -> filt_store to global;
// single writer). Phase 2: 8 batches as 4 ping-pong row-pairs reading kf4
// (L2-hot from own writes). Bias folded into Kf.
__global__ __launch_bounds__(NT) void k_main(const float* __restrict__ x, const float* __restrict__ H,
        const float* __restrict__ t, const float* __restrict__ deltas,
        const float* __restrict__ W3, const float* __restrict__ b3,
        const float* __restrict__ bias, const float* __restrict__ ws,
        float* __restrict__ KfF, float* __restrict__ out) {
    __shared__ alignas(16) cplx lds2[2][LSEQ];
    __shared__ cplx twT[16][68];
    const int c = blockIdx.x;                   // 0..767
    const int tt = threadIdx.x;
    cplx* l0 = lds2[0];
    cplx* l1 = lds2[1];
    float4* l04 = (float4*)l0;
    float4* l14 = (float4*)l1;
    float4* kf4 = (float4*)KfF + (size_t)c * 4096;
    const cplx* tw16 = (const cplx*)(ws + OFF_TW16);
    const size_t rowstride = (size_t)NCH * LSEQ;
    const float* xcol = x + (size_t)c * LSEQ;
    float* ocol = out + (size_t)c * LSEQ;
    const float sc = 1.0f / 32768.0f;

    // staging slot: IDX14(2i),IDX14(2i+1) = one float4 at ((EB^(j<<2))+(j<<10))>>1
    const int EB = (tt << 1) ^ (((tt>>3) ^ (tt>>7)) & 14);
    const int sbA = psb<0>(tt);

    load_twT(twT, ws, tt);

    // ---- Phase 1: filter for channel c -> l0 -> fwd FFT -> Kf[c] ----
    {
        float4 w3a = make_float4(W3[0*NCH+c],  W3[1*NCH+c],  W3[2*NCH+c],  W3[3*NCH+c]);
        float4 w3b = make_float4(W3[4*NCH+c],  W3[5*NCH+c],  W3[6*NCH+c],  W3[7*NCH+c]);
        float4 w3c = make_float4(W3[8*NCH+c],  W3[9*NCH+c],  W3[10*NCH+c], W3[11*NCH+c]);
        float4 w3d = make_float4(W3[12*NCH+c], W3[13*NCH+c], W3[14*NCH+c], W3[15*NCH+c]);
        const float b3c = b3[c];
        const float ad = fabsf(deltas[c]);
#pragma unroll 1
        for (int j = 0; j < 8; ++j) {
            int n = tt + (j << 9);
            const float4* hp = (const float4*)(H + (n << 5));
            float4 p0 = hp[0], p1 = hp[1], p2 = hp[2], p3 = hp[3];
            float4 q0 = hp[4], q1 = hp[5], q2 = hp[6], q3 = hp[7];
            float s0 = b3c + p0.x*w3a.x + p0.y*w3a.y + p0.z*w3a.z + p0.w*w3a.w
                           + p1.x*w3b.x + p1.y*w3b.y + p1.z*w3b.z + p1.w*w3b.w
                           + p2.x*w3c.x + p2.y*w3c.y + p2.z*w3c.z + p2.w*w3c.w
                           + p3.x*w3d.x + p3.y*w3d.y + p3.z*w3d.z + p3.w*w3d.w;
            float s1 = b3c + q0.x*w3a.x + q0.y*w3a.y + q0.z*w3a.z + q0.w*w3a.w
                           + q1.x*w3b.x + q1.y*w3b.y + q1.z*w3b.z + q1.w*w3b.w
                           + q2.x*w3c.x + q2.y*w3c.y + q2.z*w3c.z + q2.w*w3c.w
                           + q3.x*w3d.x + q3.y*w3d.y + q3.z*w3d.z + q3.w*w3d.w;
            float2 tv = ((const float2*)t)[n];
            l0[paddr<0>(sbA, j)] = cplx{s0 * expf(-tv.x*ad), s1 * expf(-tv.y*ad)};
        }
    }
    __syncthreads();                            // covers twT copy + filter staging

    r16p<0,false,true >(l0, twT, tt); __syncthreads();
    r16p<1,false,false>(l0, twT, tt); wave_sync();
    r16p<2,false,false>(l0, twT, tt); __syncthreads();

    {
        const float bc = bias[c];
        const float eb = 2.0f * bc;
#pragma unroll 1
        for (int it = 0; it < 4; ++it) {
            int k  = tt + 1 + (it << 9);   // 1..2048
            int jj = 4096 - k;             // (k=2048: idempotent dup)
            int sA = IDX14(drev(k)) >> 1, sB = IDX14(drev(jj)) >> 1;
            cplx W  = tw16[k];
            cplx Wj = cplx{-W.y, -W.x};
            filt_store(l04, kf4, k, jj, sA, sB, W, Wj, sc, eb);
        }
        if (tt == 0) filt_dc(l04, kf4, bc);
    }
    __syncthreads();   // drains kf writes (vmcnt0 before barrier) -> L2-visible

    // ---- Phase 2: 8 batches as 4 ping-pong pairs ----
#pragma unroll 1
    for (int pp = 0; pp < 4; ++pp) {            // pair = batches (2pp, 2pp+1)
        const float4* xr0 = (const float4*)(xcol + (size_t)(2*pp)     * rowstride);
        const float4* xr1 = (const float4*)(xcol + (size_t)(2*pp + 1) * rowstride);
#pragma unroll
        for (int j = 0; j < 4; ++j) {
            int si = ((EB ^ (j<<2)) + (j<<10)) >> 1;
            l04[si] = xr0[tt + (j<<9)];
            l14[si] = xr1[tt + (j<<9)];
        }
        __syncthreads();
        r16pp<0,false,true >(l0, l1, twT, tt); __syncthreads();
        r16pp<1,false,false>(l0, l1, twT, tt); wave_sync();
        r16pp<2,false,false>(l0, l1, twT, tt); __syncthreads();

        // fused fwd-r2 + spectral + inverse-r2 on both buffers; kf/tw shared
#pragma unroll 1
        for (int it = 0; it < 4; ++it) {
            int k  = tt + 1 + (it << 9);   // 1..2048
            int jj = 4096 - k;
            int sA = IDX14(drev(k)) >> 1, sB = IDX14(drev(jj)) >> 1;
            float4 kvk = kf4[k], kvj = kf4[jj];
            cplx W  = tw16[k];
            cplx Wj = cplx{-W.y, -W.x};
            spec_rows(l04, sA, sB, kvk, kvj, W, Wj);
            spec_rows(l14, sA, sB, kvk, kvj, W, Wj);
        }
        if (tt == 0) {
            float4 kv = kf4[0];
            spec_dc(l04, kv);
            spec_dc(l14, kv);
        }
        __syncthreads();

        r16pp<2,true,false>(l0, l1, twT, tt); wave_sync();
        r16pp<1,true,false>(l0, l1, twT, tt); __syncthreads();
        r16pp<0,true,false>(l0, l1, twT, tt); __syncthreads();

        float4* o0 = (float4*)(ocol + (size_t)(2*pp)     * rowstride);
        float4* o1 = (float4*)(ocol + (size_t)(2*pp + 1) * rowstride);
#pragma unroll
        for (int j = 0; j < 4; ++j) {
            int si = ((EB ^ (j<<2)) + (j<<10)) >> 1;
            float4 f0 = l04[si], f1 = l14[si];
            o0[tt + (j<<9)] = make_float4(f0.y, f0.x, f0.w, f0.z);
            o1[tt + (j<<9)] = make_float4(f1.y, f1.x, f1.w, f1.z);
        }
        if (pp < 3) __syncthreads();   // protect lds before next pair's staging
    }
}

extern "C" void kernel_launch(void* const* d_in, const int* in_sizes, int n_in,
                              void* d_out, int out_size, void* d_ws, size_t ws_size,
                              hipStream_t stream) {
    const float* x      = (const float*)d_in[0];
    const float* z      = (const float*)d_in[2];
    const float* t      = (const float*)d_in[3];
    const float* deltas = (const float*)d_in[4];
    const float* freq   = (const float*)d_in[5];
    const float* W0     = (const float*)d_in[6];
    const float* b0     = (const float*)d_in[7];
    const float* W1     = (const float*)d_in[8];
    const float* b1     = (const float*)d_in[9];
    const float* W2     = (const float*)d_in[10];
    const float* b2     = (const float*)d_in[11];
    const float* W3     = (const float*)d_in[12];
    const float* b3     = (const float*)d_in[13];
    const float* bias   = (const float*)d_in[14];
    float* out = (float*)d_out;
    float* ws  = (float*)d_ws;
    float* H   = ws + OFF_H;
    float* Kf  = ws + OFF_KF;

    hipLaunchKernelGGL(k_pre, dim3(17), dim3(512), 0, stream, z, freq, W0, b0, W1, b1, W2, b2, ws, H);
    hipLaunchKernelGGL(k_main, dim3(NCH), dim3(NT), 0, stream, x, H, t, deltas, W3, b3, bias, ws, Kf, out);
}

// Round 17
// 574.961 us; speedup vs baseline: 1.1387x; 1.0558x over previous
//
#include <hip/hip_runtime.h>
#include <math.h>

// HyenaFilter: y = irfft(rfft(x,2L) * rfft(k,2L))[..., :L] + x*bias
// Register-blocked mixed-radix [16,16,16,2] FFT. Round-17: RESTORE R14 (the
// empirical optimum, 574.8 us). Both neighbors refuted: R15 register-Kf
// (+44 VGPR -> 128-cap spill, k_main 405), R16 twA-hoist-removed (-28 VGPR ->
// LDS-pipe contention in merged phase 2, k_main 363). R14's balance: twA[15]
// in registers (VGPR 116 < 128), Kf in global (written once, read L2-hot).
//  - filter merged into k_main: 768 blocks = 3 exact rounds; phase 1 computes
//    Kf[c] (MLP staging -> pruned fwd FFT -> filt_store), phase 2 runs 8
//    batches as 4 ping-pong row-pairs reading kf4.
//  - packed f32 cplx (v_pk_*), mask-14 swizzle + b128 LDS staging/spectral/
//    epilogue, bias folded into Kf, sequential-paired passes (one barrier per
//    pass-pair), LDS twiddle tables (B/C) + register twA (pass A), wave-local
//    B<->C sync, pruned first fwd pass, merged k_pre.

#define LSEQ 8192
#define NCH 768
#define NBATCH 8
#define NT 512            // threads per block

// ws layout (float offsets)
#define OFF_TWB  0        // 32 rows x 16 cplx : W16384^{32*q*m}   (pass B; pass-A high = rows 2b)
#define OFF_TW16 1024     // 2049 cplx         : W16384^k, k<=2048
#define OFF_TL   5124     // 32 rows x 16 cplx : W16384^{2*a*m}    (pass A low)
#define OFF_TWC  6660     // 2 rows x 16 cplx  : W16384^{512*p*m}  (pass C)
#define OFF_H    10240    // 8192 x 16 floats (MLP features, row-major)
#define OFF_KF   141312   // 768 x 4096 float4 (S~, D~ per bin pair)

typedef float cplx __attribute__((ext_vector_type(2)));

__device__ __forceinline__ cplx cmul(cplx a, cplx b){
    return cplx{a.x, a.x} * b + cplx{a.y, a.y} * cplx{-b.y, b.x};
}
__device__ __forceinline__ cplx mni(cplx a){ return cplx{a.y, -a.x}; }  // * -i

// wave-local LDS producer->consumer sync (exchange confined to one wave)
__device__ __forceinline__ void wave_sync(){
    asm volatile("s_waitcnt lgkmcnt(0)" ::: "memory");
}
// scheduling fence between the two sequential buffer-passes (R9 spill fix)
__device__ __forceinline__ void fence(){
    asm volatile("" ::: "memory");
}

// bit0-preserving swizzle (mask &14): pairs {2m,2m+1} stay adjacent, fixed order
__device__ __forceinline__ int IDX14(int i){ return i ^ (((i>>4) ^ (i>>8)) & 14); }
// digit-reversal: bin k -> slot after DIF passes [16(512),16(32),16(2)] (pre-r2, slot even)
__device__ __forceinline__ int drev(int k){
    return ((k & 15) << 9) | (((k >> 4) & 15) << 5) | (((k >> 8) & 15) << 1) | (k >> 12);
}

#define C1 0.923879532511286756f
#define S1 0.382683432365089772f
#define R2 0.707106781186547524f

// natural-in DFT-16; output bin m in q[rv[m]]. FULL=false: inputs 8..15 are
// pre-duplicated copies of 0..7 (zero upper half), stage-1 add/sub skipped.
template<bool FULL>
__device__ __forceinline__ void dft16(cplx q[16]) {
    if constexpr (FULL) {
#pragma unroll
        for (int j = 0; j < 8; ++j) { cplx u=q[j], v=q[j+8]; q[j]=u+v; q[j+8]=u-v; }
    }
    q[9]  = cmul(q[9],  cplx{ C1,-S1});
    q[10] = cmul(q[10], cplx{ R2,-R2});
    q[11] = cmul(q[11], cplx{ S1,-C1});
    q[12] = mni(q[12]);
    q[13] = cmul(q[13], cplx{-S1,-C1});
    q[14] = cmul(q[14], cplx{-R2,-R2});
    q[15] = cmul(q[15], cplx{-C1,-S1});
#pragma unroll
    for (int b = 0; b < 16; b += 8) {
#pragma unroll
        for (int j = 0; j < 4; ++j) { cplx u=q[b+j], v=q[b+j+4]; q[b+j]=u+v; q[b+j+4]=u-v; }
        q[b+5] = cmul(q[b+5], cplx{ R2,-R2});
        q[b+6] = mni(q[b+6]);
        q[b+7] = cmul(q[b+7], cplx{-R2,-R2});
    }
#pragma unroll
    for (int b = 0; b < 16; b += 4) {
        cplx u0=q[b], v0=q[b+2], u1=q[b+1], v1=q[b+3];
        q[b]=u0+v0; q[b+2]=u0-v0;
        q[b+1]=u1+v1; q[b+3]=mni(u1-v1);
    }
#pragma unroll
    for (int b = 0; b < 16; b += 2) { cplx u=q[b], v=q[b+1]; q[b]=u+v; q[b+1]=u-v; }
}

// Hand-folded swizzled addressing for mask &14: IDX14(base+p+r*L) == (sb ^ C_r) + (r*L).
template<int PASS>
__device__ __forceinline__ int psb(int t) {
    if constexpr (PASS == 0) {               // L=512, p=t
        return t ^ (((t>>4) ^ (t>>8)) & 14);
    } else if constexpr (PASS == 1) {        // L=32, base=(t>>5)<<9, p=t&31
        int p = t & 31, hb = t >> 5;
        return ((hb<<9) | p) ^ (((p>>4) ^ (hb<<1)) & 14);
    } else {                                 // L=2, base=(t>>1)<<5, p=t&1
        int h = t >> 1;
        return ((h<<5) | (t&1)) ^ (((h<<1) ^ (h>>3)) & 14);
    }
}
template<int PASS>
__device__ __forceinline__ int paddr(int sb, int r) {
    if constexpr (PASS == 0)      return (sb ^ (2*(r&7))) + (r<<9);
    else if constexpr (PASS == 1) return (sb ^ (2*(r&7))) + (r<<5);
    else                          return sb ^ (r<<1);
}

// One radix-16 pass (single buffer). Pass A twiddles come from registers
// (twA[15], hoisted — thread-constant); B/C from LDS table twT[m][row].
template<int PASS, bool DIT, bool PRUNED>
__device__ __forceinline__ void r16p(cplx* lds, const cplx (*twT)[68],
                                     const cplx (&twA)[15], int t) {
    static constexpr int RV[16] = {0,8,4,12,2,10,6,14,1,9,5,13,3,11,7,15};
    const int sb = psb<PASS>(t);
    int rL = 0;
    if constexpr (PASS == 1) { rL = t & 31; }
    else if constexpr (PASS == 2) { rL = 64 + (t & 1); }
    cplx q[16];
    if constexpr (PRUNED) {
#pragma unroll
        for (int r = 0; r < 8; ++r) { q[r] = lds[paddr<PASS>(sb, r)]; q[r+8] = q[r]; }
    } else {
#pragma unroll
        for (int r = 0; r < 16; ++r) q[r] = lds[paddr<PASS>(sb, r)];
    }
    if constexpr (DIT) {
#pragma unroll
        for (int m = 1; m < 16; ++m) {
            cplx w = (PASS == 0) ? twA[m-1] : twT[m][rL];
            q[m] = cmul(q[m], w);
        }
        dft16<true>(q);
    } else {
        dft16<!PRUNED>(q);
#pragma unroll
        for (int m = 1; m < 16; ++m) {
            cplx w = (PASS == 0) ? twA[m-1] : twT[m][rL];
            q[RV[m]] = cmul(q[RV[m]], w);
        }
    }
#pragma unroll
    for (int m = 0; m < 16; ++m) lds[paddr<PASS>(sb, m)] = q[RV[m]];
}

// paired pass: two sequential single-buffer passes, one barrier interval
template<int PASS, bool DIT, bool PRUNED>
__device__ __forceinline__ void r16pp(cplx* l0, cplx* l1, const cplx (*twT)[68],
                                      const cplx (&twA)[15], int t) {
    r16p<PASS, DIT, PRUNED>(l0, twT, twA, t);
    fence();
    r16p<PASS, DIT, PRUNED>(l1, twT, twA, t);
}

// copy twiddle tables global -> LDS (transposed): 66 rows x 16 elems
__device__ __forceinline__ void load_twT(cplx (*twT)[68], const float* __restrict__ ws, int tid) {
    const cplx* gTWB = (const cplx*)(ws + OFF_TWB);
    const cplx* gTL  = (const cplx*)(ws + OFF_TL);
    const cplx* gTWC = (const cplx*)(ws + OFF_TWC);
    for (int idx = tid; idx < 16*66; idx += NT) {
        int r = idx >> 4, m = idx & 15;
        cplx v;
        if (r < 32)      v = gTWB[(r << 4) + m];
        else if (r < 64) v = gTL[((r - 32) << 4) + m];
        else             v = gTWC[((r - 64) << 4) + m];
        twT[m][r] = v;
    }
}

// hoist pass-A combined twiddles into registers (thread-constant; call after
// twT is barrier-visible). W8192^{pm} = TL[t&31][m] * TWB[2*(t>>5)][m].
__device__ __forceinline__ void make_twA(cplx (&twA)[15], const cplx (*twT)[68], int t) {
    const int rL = 32 + (t & 31);
    const int rH = (t >> 5) << 1;
#pragma unroll
    for (int m = 1; m < 16; ++m) twA[m-1] = cmul(twT[m][rL], twT[m][rH]);
}

// spectral multiply for bin pair (k, 8192-k): o1/o2 are swapped v'[k], v'[8192-k]
__device__ __forceinline__ void specpair(cplx V1, cplx V2, float4 kv, cplx W,
                                         cplx& o1, cplx& o2) {
    cplx Eh = V1 + cplx{V2.x, -V2.y};
    cplx Oh = cplx{V1.y + V2.y, V2.x - V1.x};
    cplx S = cplx{kv.x, kv.y};
    float a = W.x*kv.z, b = W.y*kv.w, cc = W.x*kv.w, dd = W.y*kv.z;
    cplx T  = cplx{a - b, cc + dd};
    cplx T2 = cplx{a + b, cc - dd};
    cplx Ep = cmul(Eh, S) + cmul(Oh, T);
    cplx Op = cmul(Eh, T2) + cmul(Oh, S);
    o1 = cplx{Ep.y + Op.x, Ep.x - Op.y};
    o2 = cplx{Op.x - Ep.y, Ep.x + Op.y};
}

// fused fwd-r2 + spectral multiply + inverse-r2 for one buffer at slot pair
__device__ __forceinline__ void spec_rows(float4* l4, int sA, int sB,
                                          float4 kvk, float4 kvj, cplx W, cplx Wj) {
    float4 fA = l4[sA], fB = l4[sB];
    cplx uA = {fA.x, fA.y}, vA = {fA.z, fA.w};
    cplx uB = {fB.x, fB.y}, vB = {fB.z, fB.w};
    cplx Vk = uA + vA, Vk4 = uA - vA;   // bins k, k+4096
    cplx Vj = uB + vB, Vj4 = uB - vB;   // bins jj, 8192-k
    cplx r1, r2, r1j, r2j;
    specpair(Vk, Vj4, kvk, W,  r1,  r2);   // v'[k],  v'[8192-k]
    specpair(Vj, Vk4, kvj, Wj, r1j, r2j);  // v'[jj], v'[4096+k]
    cplx a0 = r1 + r2j, a1 = r1 - r2j;
    cplx b0 = r1j + r2, b1 = r1j - r2;
    l4[sA] = make_float4(a0.x, a0.y, a1.x, a1.y);
    l4[sB] = make_float4(b0.x, b0.y, b1.x, b1.y);
}

// bins 0 / 4096 special (tt==0); slots {0,1} = l4[0]
__device__ __forceinline__ void spec_dc(float4* l4, float4 kv) {
    float4 f = l4[0];
    cplx u = {f.x, f.y}, v = {f.z, f.w};
    cplx V0 = u + v, VN = u - v;
    float U0 = V0.x + V0.y, UL = V0.x - V0.y;
    float re = U0*kv.x + UL*kv.y;
    float im = U0*kv.x - UL*kv.y;
    cplx s0 = {im, re};
    cplx P = {VN.x*kv.z + VN.y*kv.w, VN.x*kv.w - VN.y*kv.z};
    cplx s1 = {-P.y, P.x};
    cplx a = s0 + s1, b = s0 - s1;
    l4[0] = make_float4(a.x, a.y, b.x, b.y);
}

// filter spectral store for one channel at quad (k,jj), bias folded (E += eb)
__device__ __forceinline__ void filt_store(const float4* l4, float4* kf, int k, int jj,
                                           int sA, int sB, cplx W, cplx Wj,
                                           float sc, float eb) {
    float4 fA = l4[sA], fB = l4[sB];
    cplx uA = {fA.x, fA.y}, vA = {fA.z, fA.w};
    cplx uB = {fB.x, fB.y}, vB = {fB.z, fB.w};
    cplx Vk = uA + vA, Vk4 = uA - vA;
    cplx Vj = uB + vB, Vj4 = uB - vB;
    {
        cplx E = {Vk.x + Vj4.x + eb, Vk.y - Vj4.y};
        cplx O = {Vk.y + Vj4.y, Vj4.x - Vk.x};
        cplx D = cmul(W, O);
        kf[k] = make_float4(E.x*sc, E.y*sc, D.x*sc, D.y*sc);
    }
    {
        cplx E = {Vj.x + Vk4.x + eb, Vj.y - Vk4.y};
        cplx O = {Vj.y + Vk4.y, Vk4.x - Vj.x};
        cplx D = cmul(Wj, O);
        kf[jj] = make_float4(E.x*sc, E.y*sc, D.x*sc, D.y*sc);
    }
}
// DC store with bias fold: H[0]+=bc, H[8192]+=bc, H[4096]+=bc.
__device__ __forceinline__ void filt_dc(const float4* l4, float4* kf, float bc) {
    float4 f = l4[0];
    cplx u = {f.x, f.y}, v = {f.z, f.w};
    cplx V0 = u + v, VN = u - v;
    kf[0] = make_float4((V0.x + V0.y + bc)/16384.f, (V0.x - V0.y + bc)/16384.f,
                        (VN.x + bc)/8192.f, -VN.y/8192.f);
}

// merged init (block 0: twiddle tables via double-precision factor tables) + MLP (blocks 1..16)
__global__ __launch_bounds__(512) void k_pre(const float* __restrict__ z, const float* __restrict__ freq,
        const float* __restrict__ W0, const float* __restrict__ b0,
        const float* __restrict__ W1, const float* __restrict__ b1,
        const float* __restrict__ W2, const float* __restrict__ b2,
        float* __restrict__ ws, float* __restrict__ H) {
    __shared__ double2 lA[128], lB[128];
    const int t = threadIdx.x;
    if (blockIdx.x == 0) {
        const double K = -2.0 * 3.14159265358979323846 / 16384.0;
        if (t < 128)      { double a = K * (double)(t << 7); lA[t] = make_double2(cos(a), sin(a)); }
        else if (t < 256) { int b = t - 128; double a = K * (double)b; lB[b] = make_double2(cos(a), sin(a)); }
        __syncthreads();
        auto wf = [&](int e) -> float2 {
            e &= 16383;
            double2 A = lA[e >> 7], B = lB[e & 127];
            return make_float2((float)(A.x*B.x - A.y*B.y), (float)(A.x*B.y + A.y*B.x));
        };
        float2* tw16 = (float2*)(ws + OFF_TW16);
        for (int k = t; k <= 2048; k += 512) tw16[k] = wf(k);
        if (t < 32) {
            float2* rowL = (float2*)(ws + OFF_TL)  + (t << 4);
            float2* rowB = (float2*)(ws + OFF_TWB) + (t << 4);
#pragma unroll
            for (int m = 0; m < 16; ++m) { rowL[m] = wf(2*t*m); rowB[m] = wf(32*t*m); }
        } else if (t < 34) {
            int c2 = t - 32;
            float2* rowC = (float2*)(ws + OFF_TWC) + (c2 << 4);
#pragma unroll
            for (int m = 0; m < 16; ++m) rowC[m] = wf(512*c2*m);
        }
    } else {
        const int j = ((blockIdx.x - 1) << 9) + t;
        const float z0 = z[j*3+0], z1 = z[j*3+1], z2 = z[j*3+2];
        float h[16], g[16];
#pragma unroll
        for (int m = 0; m < 16; ++m)
            h[m] = sinf(freq[m] * (z0*W0[m] + z1*W0[16+m] + z2*W0[32+m] + b0[m]));
#pragma unroll
        for (int m = 0; m < 16; ++m) {
            float a = b1[m];
#pragma unroll
            for (int p = 0; p < 16; ++p) a += h[p] * W1[p*16+m];
            g[m] = sinf(freq[m] * a);
        }
#pragma unroll
        for (int m = 0; m < 16; ++m) {
            float a = b2[m];
#pragma unroll
            for (int p = 0; p < 16; ++p) a += g[p] * W2[p*16+m];
            h[m] = sinf(freq[m] * a);
        }
        float4* hp = (float4*)(H + (j << 4));   // row-major [8192][16]
        hp[0] = make_float4(h[0],  h[1],  h[2],  h[3]);
        hp[1] = make_float4(h[4],  h[5],  h[6],  h[7]);
        hp[2] = make_float4(h[8],  h[9],  h[10], h[11]);
        hp[3] = make_float4(h[12], h[13], h[14], h[15]);
    }
}

// Block = channel c (768 blocks = 3 exact rounds). Phase 1: compute filter
// spectrum Kf[c] (MLP staging -> pruned fwd FFT in l0 -> filt_store to global;
// single writer). Phase 2: 8 batches as 4 ping-pong row-pairs reading kf4
// (L2-hot from own writes). Bias folded into Kf.
__global__ __launch_bounds__(NT) void k_main(const float* __restrict__ x, const float* __restrict__ H,
        const float* __restrict__ t, const float* __restrict__ deltas,
        const float* __restrict__ W3, const float* __restrict__ b3,
        const float* __restrict__ bias, const float* __restrict__ ws,
        float* __restrict__ KfF, float* __restrict__ out) {
    __shared__ alignas(16) cplx lds2[2][LSEQ];
    __shared__ cplx twT[16][68];
    const int c = blockIdx.x;                   // 0..767
    const int tt = threadIdx.x;
    cplx* l0 = lds2[0];
    cplx* l1 = lds2[1];
    float4* l04 = (float4*)l0;
    float4* l14 = (float4*)l1;
    float4* kf4 = (float4*)KfF + (size_t)c * 4096;
    const cplx* tw16 = (const cplx*)(ws + OFF_TW16);
    const size_t rowstride = (size_t)NCH * LSEQ;
    const float* xcol = x + (size_t)c * LSEQ;
    float* ocol = out + (size_t)c * LSEQ;
    const float sc = 1.0f / 32768.0f;

    // staging slot: IDX14(2i),IDX14(2i+1) = one float4 at ((EB^(j<<2))+(j<<10))>>1
    const int EB = (tt << 1) ^ (((tt>>3) ^ (tt>>7)) & 14);
    const int sbA = psb<0>(tt);

    load_twT(twT, ws, tt);

    // ---- Phase 1: filter for channel c -> l0 -> fwd FFT -> Kf[c] ----
    {
        float4 w3a = make_float4(W3[0*NCH+c],  W3[1*NCH+c],  W3[2*NCH+c],  W3[3*NCH+c]);
        float4 w3b = make_float4(W3[4*NCH+c],  W3[5*NCH+c],  W3[6*NCH+c],  W3[7*NCH+c]);
        float4 w3c = make_float4(W3[8*NCH+c],  W3[9*NCH+c],  W3[10*NCH+c], W3[11*NCH+c]);
        float4 w3d = make_float4(W3[12*NCH+c], W3[13*NCH+c], W3[14*NCH+c], W3[15*NCH+c]);
        const float b3c = b3[c];
        const float ad = fabsf(deltas[c]);
#pragma unroll 1
        for (int j = 0; j < 8; ++j) {
            int n = tt + (j << 9);
            const float4* hp = (const float4*)(H + (n << 5));
            float4 p0 = hp[0], p1 = hp[1], p2 = hp[2], p3 = hp[3];
            float4 q0 = hp[4], q1 = hp[5], q2 = hp[6], q3 = hp[7];
            float s0 = b3c + p0.x*w3a.x + p0.y*w3a.y + p0.z*w3a.z + p0.w*w3a.w
                           + p1.x*w3b.x + p1.y*w3b.y + p1.z*w3b.z + p1.w*w3b.w
                           + p2.x*w3c.x + p2.y*w3c.y + p2.z*w3c.z + p2.w*w3c.w
                           + p3.x*w3d.x + p3.y*w3d.y + p3.z*w3d.z + p3.w*w3d.w;
            float s1 = b3c + q0.x*w3a.x + q0.y*w3a.y + q0.z*w3a.z + q0.w*w3a.w
                           + q1.x*w3b.x + q1.y*w3b.y + q1.z*w3b.z + q1.w*w3b.w
                           + q2.x*w3c.x + q2.y*w3c.y + q2.z*w3c.z + q2.w*w3c.w
                           + q3.x*w3d.x + q3.y*w3d.y + q3.z*w3d.z + q3.w*w3d.w;
            float2 tv = ((const float2*)t)[n];
            l0[paddr<0>(sbA, j)] = cplx{s0 * expf(-tv.x*ad), s1 * expf(-tv.y*ad)};
        }
    }
    __syncthreads();                            // covers twT copy + filter staging
    cplx twA[15];
    make_twA(twA, twT, tt);

    r16p<0,false,true >(l0, twT, twA, tt); __syncthreads();
    r16p<1,false,false>(l0, twT, twA, tt); wave_sync();
    r16p<2,false,false>(l0, twT, twA, tt); __syncthreads();

    {
        const float bc = bias[c];
        const float eb = 2.0f * bc;
#pragma unroll 1
        for (int it = 0; it < 4; ++it) {
            int k  = tt + 1 + (it << 9);   // 1..2048
            int jj = 4096 - k;             // (k=2048: idempotent dup)
            int sA = IDX14(drev(k)) >> 1, sB = IDX14(drev(jj)) >> 1;
            cplx W  = tw16[k];
            cplx Wj = cplx{-W.y, -W.x};
            filt_store(l04, kf4, k, jj, sA, sB, W, Wj, sc, eb);
        }
        if (tt == 0) filt_dc(l04, kf4, bc);
    }
    __syncthreads();   // drains kf writes (vmcnt0 before barrier) -> L2-visible

    // ---- Phase 2: 8 batches as 4 ping-pong pairs ----
#pragma unroll 1
    for (int pp = 0; pp < 4; ++pp) {            // pair = batches (2pp, 2pp+1)
        const float4* xr0 = (const float4*)(xcol + (size_t)(2*pp)     * rowstride);
        const float4* xr1 = (const float4*)(xcol + (size_t)(2*pp + 1) * rowstride);
#pragma unroll
        for (int j = 0; j < 4; ++j) {
            int si = ((EB ^ (j<<2)) + (j<<10)) >> 1;
            l04[si] = xr0[tt + (j<<9)];
            l14[si] = xr1[tt + (j<<9)];
        }
        __syncthreads();
        r16pp<0,false,true >(l0, l1, twT, twA, tt); __syncthreads();
        r16pp<1,false,false>(l0, l1, twT, twA, tt); wave_sync();
        r16pp<2,false,false>(l0, l1, twT, twA, tt); __syncthreads();

        // fused fwd-r2 + spectral + inverse-r2 on both buffers; kf/tw shared
#pragma unroll 1
        for (int it = 0; it < 4; ++it) {
            int k  = tt + 1 + (it << 9);   // 1..2048
            int jj = 4096 - k;
            int sA = IDX14(drev(k)) >> 1, sB = IDX14(drev(jj)) >> 1;
            float4 kvk = kf4[k], kvj = kf4[jj];
            cplx W  = tw16[k];
            cplx Wj = cplx{-W.y, -W.x};
            spec_rows(l04, sA, sB, kvk, kvj, W, Wj);
            spec_rows(l14, sA, sB, kvk, kvj, W, Wj);
        }
        if (tt == 0) {
            float4 kv = kf4[0];
            spec_dc(l04, kv);
            spec_dc(l14, kv);
        }
        __syncthreads();

        r16pp<2,true,false>(l0, l1, twT, twA, tt); wave_sync();
        r16pp<1,true,false>(l0, l1, twT, twA, tt); __syncthreads();
        r16pp<0,true,false>(l0, l1, twT, twA, tt); __syncthreads();

        float4* o0 = (float4*)(ocol + (size_t)(2*pp)     * rowstride);
        float4* o1 = (float4*)(ocol + (size_t)(2*pp + 1) * rowstride);
#pragma unroll
        for (int j = 0; j < 4; ++j) {
            int si = ((EB ^ (j<<2)) + (j<<10)) >> 1;
            float4 f0 = l04[si], f1 = l14[si];
            o0[tt + (j<<9)] = make_float4(f0.y, f0.x, f0.w, f0.z);
            o1[tt + (j<<9)] = make_float4(f1.y, f1.x, f1.w, f1.z);
        }
        if (pp < 3) __syncthreads();   // protect lds before next pair's staging
    }
}

extern "C" void kernel_launch(void* const* d_in, const int* in_sizes, int n_in,
                              void* d_out, int out_size, void* d_ws, size_t ws_size,
                              hipStream_t stream) {
    const float* x      = (const float*)d_in[0];
    const float* z      = (const float*)d_in[2];
    const float* t      = (const float*)d_in[3];
    const float* deltas = (const float*)d_in[4];
    const float* freq   = (const float*)d_in[5];
    const float* W0     = (const float*)d_in[6];
    const float* b0     = (const float*)d_in[7];
    const float* W1     = (const float*)d_in[8];
    const float* b1     = (const float*)d_in[9];
    const float* W2     = (const float*)d_in[10];
    const float* b2     = (const float*)d_in[11];
    const float* W3     = (const float*)d_in[12];
    const float* b3     = (const float*)d_in[13];
    const float* bias   = (const float*)d_in[14];
    float* out = (float*)d_out;
    float* ws  = (float*)d_ws;
    float* H   = ws + OFF_H;
    float* Kf  = ws + OFF_KF;

    hipLaunchKernelGGL(k_pre, dim3(17), dim3(512), 0, stream, z, freq, W0, b0, W1, b1, W2, b2, ws, H);
    hipLaunchKernelGGL(k_main, dim3(NCH), dim3(NT), 0, stream, x, H, t, deltas, W3, b3, bias, ws, Kf, out);
}